// Round 4
// baseline (307.997 us; speedup 1.0000x reference)
//
#include <hip/hip_runtime.h>

// Forward-fill: out[r,t] = att[r, last index <= t where wet==0], t=0 forced dry.
// wet is int32 (harness converts bool -> int32).
//
// Wave-persistent streaming: each WAVE owns a contiguous WSEG-elem segment of
// one row and loops over it in 256-elem chunks (4 floats/lane), chaining the
// running fill value in a register. No LDS, no __syncthreads — waves are fully
// independent. Carry-in at segment start is found by a backward ballot-search
// over preceding wet words (expected ~1 iter for random data; terminates at
// the forced-dry t=0, so correct for any input).

constexpr int WSEG   = 4096;          // elements per wave segment
constexpr int WCHUNK = 256;           // elements per iteration (64 lanes x 4)
constexpr int WITERS = WSEG / WCHUNK; // 16

__global__ __launch_bounds__(256) void ffill_wave_kernel(
    const float* __restrict__ att,
    const int* __restrict__ wet,
    float* __restrict__ out,
    int T, int segsPerRow)
{
    const int lane = threadIdx.x & 63;
    const int wid  = threadIdx.x >> 6;
    const int s    = blockIdx.x * 4 + wid;     // segment index within row
    if (s >= segsPerRow) return;               // wave-uniform exit
    const int r    = blockIdx.y;
    const long long rowBase = (long long)r * T;
    const int base = s * WSEG;

    // ---- backward lookback for the segment carry-in ----
    float carry = 0.0f;                        // unused for s==0 (t=0 forced dry)
    int hi = base;                             // exclusive upper bound
    while (hi > 0) {
        const int start = (hi >= 64) ? (hi - 64) : 0;
        const int idx   = start + lane;
        bool dry = false;
        if (idx < hi) dry = (wet[rowBase + idx] == 0) || (idx == 0);
        const unsigned long long m = __ballot(dry);
        if (m != 0ull) {
            const int src = 63 - __clzll(m);
            carry = att[rowBase + start + src]; // uniform-address broadcast load
            break;
        }
        hi = start;
    }

    // ---- prefetch iteration 0 ----
    int e = base + lane * 4;                   // element index within row
    bool valid = (e < T);                      // T % 4 == 0 -> all-or-nothing per lane
    float4 a = make_float4(0.f, 0.f, 0.f, 0.f);
    int4  wv = make_int4(1, 1, 1, 1);          // "all wet" for invalid lanes
    if (valid) {
        a  = *reinterpret_cast<const float4*>(att + rowBase + e);
        wv = *reinterpret_cast<const int4*>(wet + rowBase + e);
    }

    for (int it = 0; it < WITERS; ++it) {
        // ---- prefetch next iteration (in flight across the ballot chain) ----
        float4 a_n = make_float4(0.f, 0.f, 0.f, 0.f);
        int4  wv_n = make_int4(1, 1, 1, 1);
        bool valid_n = false;
        if (it + 1 < WITERS) {
            const int en = e + WCHUNK;
            valid_n = (en < T);
            if (valid_n) {
                a_n  = *reinterpret_cast<const float4*>(att + rowBase + en);
                wv_n = *reinterpret_cast<const int4*>(wet + rowBase + en);
            }
        }

        // ---- per-lane dry flags over 4 elements ----
        bool d0 = (wv.x == 0) || (e == 0);     // forced dry at t=0
        bool d1 = (wv.y == 0);
        bool d2 = (wv.z == 0);
        bool d3 = (wv.w == 0);
        if (!valid) { d0 = d1 = d2 = d3 = false; }

        const bool has = d0 | d1 | d2 | d3;
        // value at the LAST dry position among this lane's 4 elements
        const float lastval = d3 ? a.w : (d2 ? a.z : (d1 ? a.y : a.x));

        // ---- carry-in for this lane: rightmost dry among lower lanes, else carry ----
        const unsigned long long mask = __ballot(has);
        const unsigned long long pm = mask & ((1ull << lane) - 1ull);
        const int psrc = (pm != 0ull) ? (63 - __clzll(pm)) : 0;
        const float pval = __shfl(lastval, psrc);
        const float carry_in = (pm != 0ull) ? pval : carry;

        // ---- sequential fill over the lane's 4 elements, vector store ----
        if (valid) {
            float running = carry_in;
            float4 o;
            running = d0 ? a.x : running;  o.x = running;
            running = d1 ? a.y : running;  o.y = running;
            running = d2 ? a.z : running;  o.z = running;
            running = d3 ? a.w : running;  o.w = running;
            *reinterpret_cast<float4*>(out + rowBase + e) = o;
        }

        // ---- update the wave carry ----
        const int wsrc = (mask != 0ull) ? (63 - __clzll(mask)) : 0;
        const float wval = __shfl(lastval, wsrc);
        if (mask != 0ull) carry = wval;

        a = a_n; wv = wv_n; valid = valid_n; e += WCHUNK;
    }
}

extern "C" void kernel_launch(void* const* d_in, const int* in_sizes, int n_in,
                              void* d_out, int out_size, void* d_ws, size_t ws_size,
                              hipStream_t stream) {
    const float* att = (const float*)d_in[0];
    const int* wet   = (const int*)d_in[1];
    float* out       = (float*)d_out;

    const int B = 64;
    const int T = in_sizes[0] / B;                      // 500000
    const int segsPerRow = (T + WSEG - 1) / WSEG;       // 123
    const int blocksX = (segsPerRow + 3) / 4;           // 4 waves per block -> 31

    dim3 grid(blocksX, B);
    dim3 block(256);
    ffill_wave_kernel<<<grid, block, 0, stream>>>(att, wet, out, T, segsPerRow);
}